// Round 2
// baseline (1243.510 us; speedup 1.0000x reference)
//
#include <hip/hip_runtime.h>
#include <math.h>

#define D 256
#define N 32768
#define M 4096

// output layout (floats): quantized | loss | indices | perplexity
#define LOSS_OFF 8388608
#define IDX_OFF  8388609
#define PERP_OFF 8421377

// workspace layout (bytes)
#define WS_ENORM  0         // float[4096]
#define WS_COUNTS 16384     // uint[4096]
#define WS_IDX    32768     // int[32768]
#define WS_LPART  163840    // float[2048]
#define WS_NPART  172032    // float[2048]
#define C_BLOCKS  2048

// ---------------- K1: embedding norms + zero counts ----------------
__global__ __launch_bounds__(256) void init_kernel(const float* __restrict__ emb,
                                                   float* __restrict__ enorm,
                                                   unsigned* __restrict__ counts) {
    int tid = threadIdx.x;
    int lane = tid & 63;
    int wid = tid >> 6;
    int m = blockIdx.x * 4 + wid;
    const float4* e4 = (const float4*)(emb + (size_t)m * D);
    float4 v = e4[lane];
    float s = v.x * v.x + v.y * v.y + v.z * v.z + v.w * v.w;
    #pragma unroll
    for (int off = 32; off; off >>= 1) s += __shfl_xor(s, off);
    if (lane == 0) enorm[m] = s;
    int gid = blockIdx.x * 256 + tid;
    if (gid < M) counts[gid] = 0u;
}

// ---------------- K2: tiled distance argmin ----------------
// tile: 64 rows x 128 cols, K tiled by 64. 256 threads, 4x8 acc each.
#define BR 64
#define BC 128
#define BK 64

__global__ __launch_bounds__(256) void argmin_kernel(
    const float* __restrict__ x, const float* __restrict__ emb,
    const float* __restrict__ enorm, unsigned* __restrict__ counts,
    int* __restrict__ idx_out, float* __restrict__ idx_f)
{
    __shared__ float xs[BR][65];   // stride 65: bank-conflict-free scalar reads
    __shared__ float es[BC][65];
    __shared__ float en_s[BC];

    int tid = threadIdx.x;
    int ty = tid >> 4;   // 0..15  -> rows ty + 16*i
    int tx = tid & 15;   // 0..15  -> cols tx + 16*j
    int r0 = blockIdx.x * BR;

    float bestv[4];
    int bestc[4];
    #pragma unroll
    for (int i = 0; i < 4; ++i) { bestv[i] = 3.4e38f; bestc[i] = 0; }

    for (int ct = 0; ct < M / BC; ++ct) {
        int c0 = ct * BC;
        float acc[4][8];
        #pragma unroll
        for (int i = 0; i < 4; ++i)
            #pragma unroll
            for (int j = 0; j < 8; ++j) acc[i][j] = 0.0f;

        for (int kt = 0; kt < D / BK; ++kt) {
            __syncthreads();
            // stage x tile: 64 rows x 64 k
            #pragma unroll
            for (int p = 0; p < 4; ++p) {
                int l = p * 256 + tid;
                int r = l >> 4, k4 = l & 15;
                float4 v = *(const float4*)(x + (size_t)(r0 + r) * D + kt * BK + k4 * 4);
                xs[r][k4 * 4 + 0] = v.x; xs[r][k4 * 4 + 1] = v.y;
                xs[r][k4 * 4 + 2] = v.z; xs[r][k4 * 4 + 3] = v.w;
            }
            // stage e tile: 128 rows x 64 k
            #pragma unroll
            for (int p = 0; p < 8; ++p) {
                int l = p * 256 + tid;
                int r = l >> 4, k4 = l & 15;
                float4 v = *(const float4*)(emb + (size_t)(c0 + r) * D + kt * BK + k4 * 4);
                es[r][k4 * 4 + 0] = v.x; es[r][k4 * 4 + 1] = v.y;
                es[r][k4 * 4 + 2] = v.z; es[r][k4 * 4 + 3] = v.w;
            }
            if (kt == 0 && tid < BC) en_s[tid] = enorm[c0 + tid];
            __syncthreads();

            #pragma unroll 8
            for (int k = 0; k < BK; ++k) {
                float xv[4], ev[8];
                #pragma unroll
                for (int i = 0; i < 4; ++i) xv[i] = xs[ty + 16 * i][k];
                #pragma unroll
                for (int j = 0; j < 8; ++j) ev[j] = es[tx + 16 * j][k];
                #pragma unroll
                for (int i = 0; i < 4; ++i)
                    #pragma unroll
                    for (int j = 0; j < 8; ++j)
                        acc[i][j] = fmaf(xv[i], ev[j], acc[i][j]);
            }
        }
        // score: s = ||e||^2 - 2 x.e  (||x||^2 constant per row, argmin-invariant)
        #pragma unroll
        for (int i = 0; i < 4; ++i) {
            #pragma unroll
            for (int j = 0; j < 8; ++j) {
                int c = c0 + tx + 16 * j;
                float s = en_s[tx + 16 * j] - 2.0f * acc[i][j];
                if (s < bestv[i]) { bestv[i] = s; bestc[i] = c; }  // strict <: first idx wins
            }
        }
    }

    // reduce (val,idx) across the 16 tx lanes of each ty group
    #pragma unroll
    for (int i = 0; i < 4; ++i) {
        float v = bestv[i]; int c = bestc[i];
        #pragma unroll
        for (int off = 8; off; off >>= 1) {
            float ov = __shfl_xor(v, off, 16);
            int oc = __shfl_xor(c, off, 16);
            if (ov < v || (ov == v && oc < c)) { v = ov; c = oc; }
        }
        if (tx == 0) {
            int row = r0 + ty + 16 * i;
            idx_out[row] = c;
            idx_f[row] = (float)c;
            atomicAdd(&counts[c], 1u);
        }
    }
}

// ---------------- K3: gather + straight-through + loss partials ----------------
__global__ __launch_bounds__(256) void gather_kernel(
    const float* __restrict__ x, const float* __restrict__ emb,
    const int* __restrict__ idx, float* __restrict__ out,
    float* __restrict__ lpart, float* __restrict__ npart)
{
    int tid = threadIdx.x, lane = tid & 63, wid = tid >> 6;
    __shared__ float ls[4], ns[4];
    double lacc = 0.0, nacc = 0.0;
    for (int it = 0; it < 4; ++it) {
        int row = (blockIdx.x * 4 + wid) + it * (C_BLOCKS * 4);
        int c = idx[row];
        float4 xv = *(const float4*)(x + (size_t)row * D + lane * 4);
        float4 qv = *(const float4*)(emb + (size_t)c * D + lane * 4);
        float4 o;   // mimic x + (q - x) rounding
        o.x = xv.x + (qv.x - xv.x); o.y = xv.y + (qv.y - xv.y);
        o.z = xv.z + (qv.z - xv.z); o.w = xv.w + (qv.w - xv.w);
        *(float4*)(out + (size_t)row * D + lane * 4) = o;
        float dx = xv.x - qv.x, dy = xv.y - qv.y, dz = xv.z - qv.z, dw = xv.w - qv.w;
        float ss = dx * dx + dy * dy + dz * dz + dw * dw;
        float sa = fabsf(xv.x) + fabsf(xv.y) + fabsf(xv.z) + fabsf(xv.w);
        #pragma unroll
        for (int off = 32; off; off >>= 1) {
            ss += __shfl_xor(ss, off);
            sa += __shfl_xor(sa, off);
        }
        if (sa > 0.0f) { lacc += (double)ss * (1.0 / 256.0); nacc += 1.0; }
    }
    if (lane == 0) { ls[wid] = (float)lacc; ns[wid] = (float)nacc; }
    __syncthreads();
    if (tid == 0) {
        lpart[blockIdx.x] = ls[0] + ls[1] + ls[2] + ls[3];
        npart[blockIdx.x] = ns[0] + ns[1] + ns[2] + ns[3];
    }
}

// ---------------- K4: perplexity + loss finalize ----------------
__global__ __launch_bounds__(256) void finalize_kernel(
    const unsigned* __restrict__ counts, const float* __restrict__ lpart,
    const float* __restrict__ npart, float* __restrict__ out)
{
    __shared__ double sd[256];
    __shared__ double sl[256];
    __shared__ double sn[256];
    int tid = threadIdx.x;
    double t = 0.0;
    for (int i = tid; i < M; i += 256) {
        double p = (double)counts[i] * (1.0 / 32768.0);
        t += p * log(p + 1e-10);
    }
    sd[tid] = t;
    double ln = 0.0, nn = 0.0;
    for (int i = tid; i < C_BLOCKS; i += 256) { ln += lpart[i]; nn += npart[i]; }
    sl[tid] = ln; sn[tid] = nn;
    __syncthreads();
    for (int s = 128; s; s >>= 1) {
        if (tid < s) { sd[tid] += sd[tid + s]; sl[tid] += sl[tid + s]; sn[tid] += sn[tid + s]; }
        __syncthreads();
    }
    if (tid == 0) {
        out[PERP_OFF] = (float)exp(-sd[0]);
        out[LOSS_OFF] = (float)(0.25 * sl[0] / sn[0]);
    }
}

extern "C" void kernel_launch(void* const* d_in, const int* in_sizes, int n_in,
                              void* d_out, int out_size, void* d_ws, size_t ws_size,
                              hipStream_t stream) {
    const float* x = (const float*)d_in[0];
    const float* emb = (const float*)d_in[1];
    float* out = (float*)d_out;
    char* ws = (char*)d_ws;
    float* enorm = (float*)(ws + WS_ENORM);
    unsigned* counts = (unsigned*)(ws + WS_COUNTS);
    int* idx = (int*)(ws + WS_IDX);
    float* lpart = (float*)(ws + WS_LPART);
    float* npart = (float*)(ws + WS_NPART);

    init_kernel<<<M / 4, 256, 0, stream>>>(emb, enorm, counts);
    argmin_kernel<<<N / BR, 256, 0, stream>>>(x, emb, enorm, counts, idx, out + IDX_OFF);
    gather_kernel<<<C_BLOCKS, 256, 0, stream>>>(x, emb, idx, out, lpart, npart);
    finalize_kernel<<<1, 256, 0, stream>>>(counts, lpart, npart, out);
}

// Round 8
// 417.833 us; speedup vs baseline: 2.9761x; 2.9761x over previous
//
#include <hip/hip_runtime.h>
#include <math.h>
#include <stdint.h>

#define D 256
#define N 32768
#define M 4096

// output layout (floats): quantized | loss | indices | perplexity
#define LOSS_OFF 8388608
#define IDX_OFF  8388609
#define PERP_OFF 8421377

typedef _Float16 f16;
typedef _Float16 f16x8 __attribute__((ext_vector_type(8)));
typedef _Float16 f16x4 __attribute__((ext_vector_type(4)));
typedef float f32x4 __attribute__((ext_vector_type(4)));

// ---------- workspace layout (bytes), fp16-MFMA path ----------
#define WS_XH     0u
#define WS_XL     16777216u
#define WS_EH     33554432u
#define WS_EL     35651584u
#define WS_ENORM  37748736u
#define WS_COUNTS 37765120u
#define WS_IDX    37781504u
#define WS_CAND   37912576u   // float2[4][32768]
#define WS_LPART  38961152u
#define WS_NPART  38969344u
#define WS_NEEDED 38977536u
#define C_BLOCKS  2048

__device__ __forceinline__ void gload16(const void* g, void* l) {
    __builtin_amdgcn_global_load_lds(
        (const __attribute__((address_space(1))) uint32_t*)g,
        (__attribute__((address_space(3))) uint32_t*)l, 16, 0, 0);
}

// ---------------- K1: embedding norms + zero counts ----------------
__global__ __launch_bounds__(256) void init_kernel(const float* __restrict__ emb,
                                                   float* __restrict__ enorm,
                                                   unsigned* __restrict__ counts) {
    int tid = threadIdx.x;
    int lane = tid & 63;
    int wid = tid >> 6;
    int m = blockIdx.x * 4 + wid;
    const float4* e4 = (const float4*)(emb + (size_t)m * D);
    float4 v = e4[lane];
    float s = v.x * v.x + v.y * v.y + v.z * v.z + v.w * v.w;
    #pragma unroll
    for (int off = 32; off; off >>= 1) s += __shfl_xor(s, off);
    if (lane == 0) enorm[m] = s;
    int gid = blockIdx.x * 256 + tid;
    if (gid < M) counts[gid] = 0u;
}

// ---------------- convert: f32 -> (hi fp16, lo fp16) ----------------
__global__ __launch_bounds__(256) void convert_kernel(const float* __restrict__ s,
                                                      f16* __restrict__ dh,
                                                      f16* __restrict__ dl, int n4) {
    int i = blockIdx.x * 256 + threadIdx.x;
    if (i >= n4) return;
    float4 v = ((const float4*)s)[i];
    f16 h0 = (f16)v.x, h1 = (f16)v.y, h2 = (f16)v.z, h3 = (f16)v.w;
    f16 l0 = (f16)(v.x - (float)h0), l1 = (f16)(v.y - (float)h1);
    f16 l2 = (f16)(v.z - (float)h2), l3 = (f16)(v.w - (float)h3);
    f16x4 hv; hv[0] = h0; hv[1] = h1; hv[2] = h2; hv[3] = h3;
    f16x4 lv; lv[0] = l0; lv[1] = l1; lv[2] = l2; lv[3] = l3;
    *(f16x4*)(dh + (size_t)i * 4) = hv;
    *(f16x4*)(dl + (size_t)i * 4) = lv;
}

// ---------------- K2 (MFMA): distance argmin via fp16 split ----------------
// x.e ~= xh.eh + xh.el + xl.eh  -> K=3*256, BK=64, tile 128rows x 128cols,
// 4 waves (2x2), 64x64 per wave, mfma_f32_16x16x32_f16.
// grid: (rb 0..255) x (cs 0..3); block cs handles col-tiles cs*8..cs*8+7.
// wc halves merged in LDS before the cand write (round-3 race fix).
__global__ __launch_bounds__(256) void argmin_mfma(
    const f16* __restrict__ xh, const f16* __restrict__ xl,
    const f16* __restrict__ eh, const f16* __restrict__ el,
    const float* __restrict__ enorm, float2* __restrict__ cand)
{
    __shared__ f16 Als[128][64];   // 16 KB, linear (gload_lds dest must be linear)
    __shared__ f16 Bls[128][64];   // 16 KB
    __shared__ float2 msm[2][64];  // wc=1 waves' reduced (v,c), keyed [wr][rowloc]

    int tid = threadIdx.x;
    int lane = tid & 63;
    int wid = tid >> 6;
    int wr = wid >> 1, wc = wid & 1;
    int rb = blockIdx.x >> 2;
    int cs = blockIdx.x & 3;
    int row0 = rb * 128;

    // staging: wave w covers chunks w*4..w*4+3 (1 KB each); lane l -> +l*16B
    int srow = lane >> 3;          // row within chunk's 8 rows
    int sk = (lane & 7) * 8;       // fp16 element offset within row

    float bestv[4][4];
    int bestc[4][4];
    #pragma unroll
    for (int i = 0; i < 4; ++i)
        #pragma unroll
        for (int r = 0; r < 4; ++r) { bestv[i][r] = 3.4e38f; bestc[i][r] = 0; }

    for (int ct = 0; ct < 8; ++ct) {
        int c0 = (cs * 8 + ct) * 128;
        f32x4 acc[4][4];
        #pragma unroll
        for (int i = 0; i < 4; ++i)
            #pragma unroll
            for (int j = 0; j < 4; ++j) acc[i][j] = (f32x4)0.0f;

        for (int seg = 0; seg < 3; ++seg) {
            const f16* Ap = (seg == 2) ? xl : xh;
            const f16* Bp = (seg == 1) ? el : eh;
            for (int kt = 0; kt < 4; ++kt) {
                int k0 = kt * 64;
                __syncthreads();
                #pragma unroll
                for (int q = 0; q < 4; ++q) {
                    int ch = wid * 4 + q;         // 0..15
                    int tr = ch * 8 + srow;       // tile row 0..127
                    gload16(Ap + (size_t)(row0 + tr) * D + k0 + sk,
                            (char*)&Als[0][0] + ch * 1024);
                    gload16(Bp + (size_t)(c0 + tr) * D + k0 + sk,
                            (char*)&Bls[0][0] + ch * 1024);
                }
                __syncthreads();
                #pragma unroll
                for (int ks = 0; ks < 2; ++ks) {
                    int ko = ks * 32 + (lane >> 4) * 8;
                    int ar = wr * 64 + (lane & 15);
                    int br = wc * 64 + (lane & 15);
                    f16x8 a[4], b[4];
                    #pragma unroll
                    for (int i = 0; i < 4; ++i) a[i] = *(const f16x8*)&Als[ar + i * 16][ko];
                    #pragma unroll
                    for (int j = 0; j < 4; ++j) b[j] = *(const f16x8*)&Bls[br + j * 16][ko];
                    #pragma unroll
                    for (int i = 0; i < 4; ++i)
                        #pragma unroll
                        for (int j = 0; j < 4; ++j)
                            acc[i][j] = __builtin_amdgcn_mfma_f32_16x16x32_f16(
                                a[i], b[j], acc[i][j], 0, 0, 0);
                }
            }
        }
        // score = ||e||^2 - 2 x.e ; cols ascend with (ct, j) -> strict < keeps first
        float enj[4];
        #pragma unroll
        for (int j = 0; j < 4; ++j) enj[j] = enorm[c0 + wc * 64 + j * 16 + (lane & 15)];
        #pragma unroll
        for (int i = 0; i < 4; ++i)
            #pragma unroll
            for (int j = 0; j < 4; ++j) {
                int c = c0 + wc * 64 + j * 16 + (lane & 15);
                #pragma unroll
                for (int r = 0; r < 4; ++r) {
                    float s = enj[j] - 2.0f * acc[i][j][r];
                    if (s < bestv[i][r]) { bestv[i][r] = s; bestc[i][r] = c; }
                }
            }
    }

    // reduce across the 16 lanes (lane&15) holding the same rows
    float rv[4][4]; int rc[4][4];
    #pragma unroll
    for (int i = 0; i < 4; ++i)
        #pragma unroll
        for (int r = 0; r < 4; ++r) {
            float v = bestv[i][r]; int c = bestc[i][r];
            #pragma unroll
            for (int off = 8; off; off >>= 1) {
                float ov = __shfl_xor(v, off);
                int oc = __shfl_xor(c, off);
                if (ov < v || (ov == v && oc < c)) { v = ov; c = oc; }
            }
            rv[i][r] = v; rc[i][r] = c;
            if ((lane & 15) == 0 && wc == 1) {
                int rloc = i * 16 + (lane >> 4) * 4 + r;
                float2 p; p.x = v; p.y = __int_as_float(c);
                msm[wr][rloc] = p;
            }
        }
    __syncthreads();
    // wc=0 waves merge the wc=1 half and write the block's candidate
    if (wc == 0 && (lane & 15) == 0) {
        #pragma unroll
        for (int i = 0; i < 4; ++i)
            #pragma unroll
            for (int r = 0; r < 4; ++r) {
                int rloc = i * 16 + (lane >> 4) * 4 + r;
                float v = rv[i][r]; int c = rc[i][r];
                float2 o = msm[wr][rloc];
                float ov = o.x; int oc = __float_as_int(o.y);
                if (ov < v || (ov == v && oc < c)) { v = ov; c = oc; }
                float2 p; p.x = v; p.y = __int_as_float(c);
                cand[(size_t)cs * N + row0 + wr * 64 + rloc] = p;
            }
    }
}

// ---------------- merge 4 col-split candidates ----------------
__global__ __launch_bounds__(256) void merge_kernel(const float2* __restrict__ cand,
                                                    unsigned* __restrict__ counts,
                                                    int* __restrict__ idx_out,
                                                    float* __restrict__ idx_f) {
    int row = blockIdx.x * 256 + threadIdx.x;
    float bv = 3.4e38f; int bc = 0;
    #pragma unroll
    for (int cs = 0; cs < 4; ++cs) {
        float2 p = cand[(size_t)cs * N + row];
        int c = __float_as_int(p.y);
        if (p.x < bv || (p.x == bv && c < bc)) { bv = p.x; bc = c; }
    }
    idx_out[row] = bc;
    idx_f[row] = (float)bc;
    atomicAdd(&counts[bc], 1u);
}

// ---------------- fp32 fallback argmin (round-2 proven) ----------------
#define BR 64
#define BC 128
#define BK 64
__global__ __launch_bounds__(256) void argmin_fp32(
    const float* __restrict__ x, const float* __restrict__ emb,
    const float* __restrict__ enorm, unsigned* __restrict__ counts,
    int* __restrict__ idx_out, float* __restrict__ idx_f)
{
    __shared__ float xs[BR][65];
    __shared__ float es[BC][65];
    __shared__ float en_s[BC];
    int tid = threadIdx.x;
    int ty = tid >> 4, tx = tid & 15;
    int r0 = blockIdx.x * BR;
    float bestv[4]; int bestc[4];
    #pragma unroll
    for (int i = 0; i < 4; ++i) { bestv[i] = 3.4e38f; bestc[i] = 0; }
    for (int ct = 0; ct < M / BC; ++ct) {
        int c0 = ct * BC;
        float acc[4][8];
        #pragma unroll
        for (int i = 0; i < 4; ++i)
            #pragma unroll
            for (int j = 0; j < 8; ++j) acc[i][j] = 0.0f;
        for (int kt = 0; kt < D / BK; ++kt) {
            __syncthreads();
            #pragma unroll
            for (int p = 0; p < 4; ++p) {
                int l = p * 256 + tid, r = l >> 4, k4 = l & 15;
                float4 v = *(const float4*)(x + (size_t)(r0 + r) * D + kt * BK + k4 * 4);
                xs[r][k4 * 4] = v.x; xs[r][k4 * 4 + 1] = v.y;
                xs[r][k4 * 4 + 2] = v.z; xs[r][k4 * 4 + 3] = v.w;
            }
            #pragma unroll
            for (int p = 0; p < 8; ++p) {
                int l = p * 256 + tid, r = l >> 4, k4 = l & 15;
                float4 v = *(const float4*)(emb + (size_t)(c0 + r) * D + kt * BK + k4 * 4);
                es[r][k4 * 4] = v.x; es[r][k4 * 4 + 1] = v.y;
                es[r][k4 * 4 + 2] = v.z; es[r][k4 * 4 + 3] = v.w;
            }
            if (kt == 0 && tid < BC) en_s[tid] = enorm[c0 + tid];
            __syncthreads();
            #pragma unroll 8
            for (int k = 0; k < BK; ++k) {
                float xv[4], ev[8];
                #pragma unroll
                for (int i = 0; i < 4; ++i) xv[i] = xs[ty + 16 * i][k];
                #pragma unroll
                for (int j = 0; j < 8; ++j) ev[j] = es[tx + 16 * j][k];
                #pragma unroll
                for (int i = 0; i < 4; ++i)
                    #pragma unroll
                    for (int j = 0; j < 8; ++j)
                        acc[i][j] = fmaf(xv[i], ev[j], acc[i][j]);
            }
        }
        #pragma unroll
        for (int i = 0; i < 4; ++i)
            #pragma unroll
            for (int j = 0; j < 8; ++j) {
                int c = c0 + tx + 16 * j;
                float s = en_s[tx + 16 * j] - 2.0f * acc[i][j];
                if (s < bestv[i]) { bestv[i] = s; bestc[i] = c; }
            }
    }
    #pragma unroll
    for (int i = 0; i < 4; ++i) {
        float v = bestv[i]; int c = bestc[i];
        #pragma unroll
        for (int off = 8; off; off >>= 1) {
            float ov = __shfl_xor(v, off, 16);
            int oc = __shfl_xor(c, off, 16);
            if (ov < v || (ov == v && oc < c)) { v = ov; c = oc; }
        }
        if (tx == 0) {
            int row = r0 + ty + 16 * i;
            idx_out[row] = c; idx_f[row] = (float)c;
            atomicAdd(&counts[c], 1u);
        }
    }
}

// ---------------- K3: gather + straight-through + loss partials ----------------
__global__ __launch_bounds__(256) void gather_kernel(
    const float* __restrict__ x, const float* __restrict__ emb,
    const int* __restrict__ idx, float* __restrict__ out,
    float* __restrict__ lpart, float* __restrict__ npart)
{
    int tid = threadIdx.x, lane = tid & 63, wid = tid >> 6;
    __shared__ float ls[4], ns[4];
    double lacc = 0.0, nacc = 0.0;
    for (int it = 0; it < 4; ++it) {
        int row = (blockIdx.x * 4 + wid) + it * (C_BLOCKS * 4);
        int c = idx[row];
        float4 xv = *(const float4*)(x + (size_t)row * D + lane * 4);
        float4 qv = *(const float4*)(emb + (size_t)c * D + lane * 4);
        float4 o;
        o.x = xv.x + (qv.x - xv.x); o.y = xv.y + (qv.y - xv.y);
        o.z = xv.z + (qv.z - xv.z); o.w = xv.w + (qv.w - xv.w);
        *(float4*)(out + (size_t)row * D + lane * 4) = o;
        float dx = xv.x - qv.x, dy = xv.y - qv.y, dz = xv.z - qv.z, dw = xv.w - qv.w;
        float ss = dx * dx + dy * dy + dz * dz + dw * dw;
        float sa = fabsf(xv.x) + fabsf(xv.y) + fabsf(xv.z) + fabsf(xv.w);
        #pragma unroll
        for (int off = 32; off; off >>= 1) {
            ss += __shfl_xor(ss, off);
            sa += __shfl_xor(sa, off);
        }
        if (sa > 0.0f) { lacc += (double)ss * (1.0 / 256.0); nacc += 1.0; }
    }
    if (lane == 0) { ls[wid] = (float)lacc; ns[wid] = (float)nacc; }
    __syncthreads();
    if (tid == 0) {
        lpart[blockIdx.x] = ls[0] + ls[1] + ls[2] + ls[3];
        npart[blockIdx.x] = ns[0] + ns[1] + ns[2] + ns[3];
    }
}

// ---------------- K4: perplexity + loss finalize ----------------
__global__ __launch_bounds__(256) void finalize_kernel(
    const unsigned* __restrict__ counts, const float* __restrict__ lpart,
    const float* __restrict__ npart, float* __restrict__ out)
{
    __shared__ double sd[256];
    __shared__ double sl[256];
    __shared__ double sn[256];
    int tid = threadIdx.x;
    double t = 0.0;
    for (int i = tid; i < M; i += 256) {
        double p = (double)counts[i] * (1.0 / 32768.0);
        t += p * log(p + 1e-10);
    }
    sd[tid] = t;
    double ln = 0.0, nn = 0.0;
    for (int i = tid; i < C_BLOCKS; i += 256) { ln += lpart[i]; nn += npart[i]; }
    sl[tid] = ln; sn[tid] = nn;
    __syncthreads();
    for (int s = 128; s; s >>= 1) {
        if (tid < s) { sd[tid] += sd[tid + s]; sl[tid] += sl[tid + s]; sn[tid] += sn[tid + s]; }
        __syncthreads();
    }
    if (tid == 0) {
        out[PERP_OFF] = (float)exp(-sd[0]);
        out[LOSS_OFF] = (float)(0.25 * sl[0] / sn[0]);
    }
}

extern "C" void kernel_launch(void* const* d_in, const int* in_sizes, int n_in,
                              void* d_out, int out_size, void* d_ws, size_t ws_size,
                              hipStream_t stream) {
    const float* x = (const float*)d_in[0];
    const float* emb = (const float*)d_in[1];
    float* out = (float*)d_out;
    char* ws = (char*)d_ws;

    float* enorm = (float*)(ws + WS_ENORM);
    unsigned* counts = (unsigned*)(ws + WS_COUNTS);
    int* idx = (int*)(ws + WS_IDX);
    float* lpart = (float*)(ws + WS_LPART);
    float* npart = (float*)(ws + WS_NPART);

    if (ws_size >= (size_t)WS_NEEDED) {
        f16* xh = (f16*)(ws + WS_XH);
        f16* xl = (f16*)(ws + WS_XL);
        f16* eh = (f16*)(ws + WS_EH);
        f16* el = (f16*)(ws + WS_EL);
        float2* cand = (float2*)(ws + WS_CAND);

        init_kernel<<<M / 4, 256, 0, stream>>>(emb, enorm, counts);
        convert_kernel<<<(N * D / 4) / 256, 256, 0, stream>>>(x, xh, xl, N * D / 4);
        convert_kernel<<<(M * D / 4) / 256, 256, 0, stream>>>(emb, eh, el, M * D / 4);
        argmin_mfma<<<1024, 256, 0, stream>>>(xh, xl, eh, el, enorm, cand);
        merge_kernel<<<N / 256, 256, 0, stream>>>(cand, counts, idx, out + IDX_OFF);
    } else {
        // fallback: small-ws layout (round-2 proven)
        enorm = (float*)(ws + 0);
        counts = (unsigned*)(ws + 16384);
        idx = (int*)(ws + 32768);
        lpart = (float*)(ws + 163840);
        npart = (float*)(ws + 172032);
        init_kernel<<<M / 4, 256, 0, stream>>>(emb, enorm, counts);
        argmin_fp32<<<N / BR, 256, 0, stream>>>(x, emb, enorm, counts, idx, out + IDX_OFF);
    }
    gather_kernel<<<C_BLOCKS, 256, 0, stream>>>(x, emb, idx, out, lpart, npart);
    finalize_kernel<<<1, 256, 0, stream>>>(counts, lpart, npart, out);
}

// Round 9
// 340.598 us; speedup vs baseline: 3.6510x; 1.2268x over previous
//
#include <hip/hip_runtime.h>
#include <math.h>
#include <stdint.h>

#define D 256
#define N 32768
#define M 4096

// output layout (floats): quantized | loss | indices | perplexity
#define LOSS_OFF 8388608
#define IDX_OFF  8388609
#define PERP_OFF 8421377

typedef _Float16 f16;
typedef _Float16 f16x8 __attribute__((ext_vector_type(8)));
typedef _Float16 f16x4 __attribute__((ext_vector_type(4)));
typedef float f32x4 __attribute__((ext_vector_type(4)));

// ---------- workspace layout (bytes), fp16-MFMA path ----------
#define WS_XH     0u
#define WS_XL     16777216u
#define WS_EH     33554432u
#define WS_EL     35651584u
#define WS_ENORM  37748736u
#define WS_COUNTS 37765120u
#define WS_IDX    37781504u
#define WS_CAND   37912576u   // float2[4][32768]
#define WS_LPART  38961152u
#define WS_NPART  38969344u
#define WS_NEEDED 38977536u
#define C_BLOCKS  2048

__device__ __forceinline__ void gload16(const void* g, void* l) {
    __builtin_amdgcn_global_load_lds(
        (const __attribute__((address_space(1))) uint32_t*)g,
        (__attribute__((address_space(3))) uint32_t*)l, 16, 0, 0);
}

// ---------------- K1: embedding norms + zero counts ----------------
__global__ __launch_bounds__(256) void init_kernel(const float* __restrict__ emb,
                                                   float* __restrict__ enorm,
                                                   unsigned* __restrict__ counts) {
    int tid = threadIdx.x;
    int lane = tid & 63;
    int wid = tid >> 6;
    int m = blockIdx.x * 4 + wid;
    const float4* e4 = (const float4*)(emb + (size_t)m * D);
    float4 v = e4[lane];
    float s = v.x * v.x + v.y * v.y + v.z * v.z + v.w * v.w;
    #pragma unroll
    for (int off = 32; off; off >>= 1) s += __shfl_xor(s, off);
    if (lane == 0) enorm[m] = s;
    int gid = blockIdx.x * 256 + tid;
    if (gid < M) counts[gid] = 0u;
}

// ---------------- convert: f32 -> (hi fp16, lo fp16) ----------------
__global__ __launch_bounds__(256) void convert_kernel(const float* __restrict__ s,
                                                      f16* __restrict__ dh,
                                                      f16* __restrict__ dl, int n4) {
    int i = blockIdx.x * 256 + threadIdx.x;
    if (i >= n4) return;
    float4 v = ((const float4*)s)[i];
    f16 h0 = (f16)v.x, h1 = (f16)v.y, h2 = (f16)v.z, h3 = (f16)v.w;
    f16 l0 = (f16)(v.x - (float)h0), l1 = (f16)(v.y - (float)h1);
    f16 l2 = (f16)(v.z - (float)h2), l3 = (f16)(v.w - (float)h3);
    f16x4 hv; hv[0] = h0; hv[1] = h1; hv[2] = h2; hv[3] = h3;
    f16x4 lv; lv[0] = l0; lv[1] = l1; lv[2] = l2; lv[3] = l3;
    *(f16x4*)(dh + (size_t)i * 4) = hv;
    *(f16x4*)(dl + (size_t)i * 4) = lv;
}

// ---------------- K2 (MFMA): distance argmin via fp16 split ----------------
// x.e ~= xh.eh + xh.el + xl.eh. Per (ct,kt): stage ALL 4 distinct tiles
// (xh,xl,eh,el = 64 KB) once, then 2 ks x {16 ds_read_b128 + 48 MFMA}.
// LDS slot-XOR swizzle (slot ^= row&7) applied via pre-swizzled global
// source (gload_lds dest stays linear) + swizzled read addr [rule #21].
// grid: (rb 0..255) x (cs 0..3). wc halves merged in LDS (round-3 fix).
__global__ __launch_bounds__(256) void argmin_mfma(
    const f16* __restrict__ xh, const f16* __restrict__ xl,
    const f16* __restrict__ eh, const f16* __restrict__ el,
    const float* __restrict__ enorm, float2* __restrict__ cand)
{
    __shared__ f16 Als[2][128][64];  // 32 KB: [xh/xl][row][k-slot swizzled]
    __shared__ f16 Bls[2][128][64];  // 32 KB: [eh/el]
    __shared__ float2 msm[2][64];    // wc=1 reduced (v,c), keyed [wr][rowloc]

    int tid = threadIdx.x;
    int lane = tid & 63;
    int wid = tid >> 6;
    int wr = wid >> 1, wc = wid & 1;
    int rb = blockIdx.x >> 2;
    int cs = blockIdx.x & 3;
    int row0 = rb * 128;

    // staging: chunk ch = 8 rows x 128 B; lane l -> row ch*8+(l>>3).
    // source col slot pre-swizzled: slot = (l&7) ^ (l>>3)  (16B slots)
    int srow = lane >> 3;
    int sk = (((lane & 7) ^ srow) * 8);   // f16 element offset in row

    // read side: rows ar+i*16 all have (row&7) == lane&7
    int rxor = lane & 7;

    float bestv[4][4];
    int bestc[4][4];
    #pragma unroll
    for (int i = 0; i < 4; ++i)
        #pragma unroll
        for (int r = 0; r < 4; ++r) { bestv[i][r] = 3.4e38f; bestc[i][r] = 0; }

    for (int ct = 0; ct < 8; ++ct) {
        int c0 = (cs * 8 + ct) * 128;
        f32x4 acc[4][4];
        #pragma unroll
        for (int i = 0; i < 4; ++i)
            #pragma unroll
            for (int j = 0; j < 4; ++j) acc[i][j] = (f32x4)0.0f;

        for (int kt = 0; kt < 4; ++kt) {
            int k0 = kt * 64;
            __syncthreads();   // prior compute done with LDS
            #pragma unroll
            for (int q = 0; q < 4; ++q) {
                int ch = wid * 4 + q;        // 0..15
                int tr = ch * 8 + srow;      // tile row 0..127
                size_t aoff = (size_t)(row0 + tr) * D + k0 + sk;
                size_t boff = (size_t)(c0 + tr) * D + k0 + sk;
                gload16(xh + aoff, (char*)&Als[0][0][0] + ch * 1024);
                gload16(xl + aoff, (char*)&Als[1][0][0] + ch * 1024);
                gload16(eh + boff, (char*)&Bls[0][0][0] + ch * 1024);
                gload16(el + boff, (char*)&Bls[1][0][0] + ch * 1024);
            }
            __syncthreads();   // staging visible (vmcnt drained by barrier)

            #pragma unroll
            for (int ks = 0; ks < 2; ++ks) {
                int slot = ks * 4 + (lane >> 4);       // 0..7
                int sw = ((slot ^ rxor) * 8);          // swizzled f16 col
                int ar = wr * 64 + (lane & 15);
                int br = wc * 64 + (lane & 15);
                f16x8 ah[4], al[4], bh[4], bl[4];
                #pragma unroll
                for (int i = 0; i < 4; ++i) {
                    ah[i] = *(const f16x8*)&Als[0][ar + i * 16][sw];
                    al[i] = *(const f16x8*)&Als[1][ar + i * 16][sw];
                }
                #pragma unroll
                for (int j = 0; j < 4; ++j) {
                    bh[j] = *(const f16x8*)&Bls[0][br + j * 16][sw];
                    bl[j] = *(const f16x8*)&Bls[1][br + j * 16][sw];
                }
                #pragma unroll
                for (int i = 0; i < 4; ++i)
                    #pragma unroll
                    for (int j = 0; j < 4; ++j)
                        acc[i][j] = __builtin_amdgcn_mfma_f32_16x16x32_f16(
                            ah[i], bh[j], acc[i][j], 0, 0, 0);
                #pragma unroll
                for (int i = 0; i < 4; ++i)
                    #pragma unroll
                    for (int j = 0; j < 4; ++j)
                        acc[i][j] = __builtin_amdgcn_mfma_f32_16x16x32_f16(
                            ah[i], bl[j], acc[i][j], 0, 0, 0);
                #pragma unroll
                for (int i = 0; i < 4; ++i)
                    #pragma unroll
                    for (int j = 0; j < 4; ++j)
                        acc[i][j] = __builtin_amdgcn_mfma_f32_16x16x32_f16(
                            al[i], bh[j], acc[i][j], 0, 0, 0);
            }
        }
        // score = ||e||^2 - 2 x.e ; cols ascend with (ct, j) -> strict < keeps first
        float enj[4];
        #pragma unroll
        for (int j = 0; j < 4; ++j) enj[j] = enorm[c0 + wc * 64 + j * 16 + (lane & 15)];
        #pragma unroll
        for (int i = 0; i < 4; ++i)
            #pragma unroll
            for (int j = 0; j < 4; ++j) {
                int c = c0 + wc * 64 + j * 16 + (lane & 15);
                #pragma unroll
                for (int r = 0; r < 4; ++r) {
                    float s = enj[j] - 2.0f * acc[i][j][r];
                    if (s < bestv[i][r]) { bestv[i][r] = s; bestc[i][r] = c; }
                }
            }
    }

    // reduce across the 16 lanes (lane&15) holding the same rows
    float rv[4][4]; int rc[4][4];
    #pragma unroll
    for (int i = 0; i < 4; ++i)
        #pragma unroll
        for (int r = 0; r < 4; ++r) {
            float v = bestv[i][r]; int c = bestc[i][r];
            #pragma unroll
            for (int off = 8; off; off >>= 1) {
                float ov = __shfl_xor(v, off);
                int oc = __shfl_xor(c, off);
                if (ov < v || (ov == v && oc < c)) { v = ov; c = oc; }
            }
            rv[i][r] = v; rc[i][r] = c;
            if ((lane & 15) == 0 && wc == 1) {
                int rloc = i * 16 + (lane >> 4) * 4 + r;
                float2 p; p.x = v; p.y = __int_as_float(c);
                msm[wr][rloc] = p;
            }
        }
    __syncthreads();
    // wc=0 waves merge the wc=1 half and write the block's candidate
    if (wc == 0 && (lane & 15) == 0) {
        #pragma unroll
        for (int i = 0; i < 4; ++i)
            #pragma unroll
            for (int r = 0; r < 4; ++r) {
                int rloc = i * 16 + (lane >> 4) * 4 + r;
                float v = rv[i][r]; int c = rc[i][r];
                float2 o = msm[wr][rloc];
                float ov = o.x; int oc = __float_as_int(o.y);
                if (ov < v || (ov == v && oc < c)) { v = ov; c = oc; }
                float2 p; p.x = v; p.y = __int_as_float(c);
                cand[(size_t)cs * N + row0 + wr * 64 + rloc] = p;
            }
    }
}

// ---------------- merge 4 col-split candidates ----------------
__global__ __launch_bounds__(256) void merge_kernel(const float2* __restrict__ cand,
                                                    unsigned* __restrict__ counts,
                                                    int* __restrict__ idx_out,
                                                    float* __restrict__ idx_f) {
    int row = blockIdx.x * 256 + threadIdx.x;
    float bv = 3.4e38f; int bc = 0;
    #pragma unroll
    for (int cs = 0; cs < 4; ++cs) {
        float2 p = cand[(size_t)cs * N + row];
        int c = __float_as_int(p.y);
        if (p.x < bv || (p.x == bv && c < bc)) { bv = p.x; bc = c; }
    }
    idx_out[row] = bc;
    idx_f[row] = (float)bc;
    atomicAdd(&counts[bc], 1u);
}

// ---------------- fp32 fallback argmin (round-2 proven) ----------------
#define BR 64
#define BC 128
#define BK 64
__global__ __launch_bounds__(256) void argmin_fp32(
    const float* __restrict__ x, const float* __restrict__ emb,
    const float* __restrict__ enorm, unsigned* __restrict__ counts,
    int* __restrict__ idx_out, float* __restrict__ idx_f)
{
    __shared__ float xs[BR][65];
    __shared__ float es[BC][65];
    __shared__ float en_s[BC];
    int tid = threadIdx.x;
    int ty = tid >> 4, tx = tid & 15;
    int r0 = blockIdx.x * BR;
    float bestv[4]; int bestc[4];
    #pragma unroll
    for (int i = 0; i < 4; ++i) { bestv[i] = 3.4e38f; bestc[i] = 0; }
    for (int ct = 0; ct < M / BC; ++ct) {
        int c0 = ct * BC;
        float acc[4][8];
        #pragma unroll
        for (int i = 0; i < 4; ++i)
            #pragma unroll
            for (int j = 0; j < 8; ++j) acc[i][j] = 0.0f;
        for (int kt = 0; kt < D / BK; ++kt) {
            __syncthreads();
            #pragma unroll
            for (int p = 0; p < 4; ++p) {
                int l = p * 256 + tid, r = l >> 4, k4 = l & 15;
                float4 v = *(const float4*)(x + (size_t)(r0 + r) * D + kt * BK + k4 * 4);
                xs[r][k4 * 4] = v.x; xs[r][k4 * 4 + 1] = v.y;
                xs[r][k4 * 4 + 2] = v.z; xs[r][k4 * 4 + 3] = v.w;
            }
            #pragma unroll
            for (int p = 0; p < 8; ++p) {
                int l = p * 256 + tid, r = l >> 4, k4 = l & 15;
                float4 v = *(const float4*)(emb + (size_t)(c0 + r) * D + kt * BK + k4 * 4);
                es[r][k4 * 4] = v.x; es[r][k4 * 4 + 1] = v.y;
                es[r][k4 * 4 + 2] = v.z; es[r][k4 * 4 + 3] = v.w;
            }
            if (kt == 0 && tid < BC) en_s[tid] = enorm[c0 + tid];
            __syncthreads();
            #pragma unroll 8
            for (int k = 0; k < BK; ++k) {
                float xv[4], ev[8];
                #pragma unroll
                for (int i = 0; i < 4; ++i) xv[i] = xs[ty + 16 * i][k];
                #pragma unroll
                for (int j = 0; j < 8; ++j) ev[j] = es[tx + 16 * j][k];
                #pragma unroll
                for (int i = 0; i < 4; ++i)
                    #pragma unroll
                    for (int j = 0; j < 8; ++j)
                        acc[i][j] = fmaf(xv[i], ev[j], acc[i][j]);
            }
        }
        #pragma unroll
        for (int i = 0; i < 4; ++i)
            #pragma unroll
            for (int j = 0; j < 8; ++j) {
                int c = c0 + tx + 16 * j;
                float s = en_s[tx + 16 * j] - 2.0f * acc[i][j];
                if (s < bestv[i]) { bestv[i] = s; bestc[i] = c; }
            }
    }
    #pragma unroll
    for (int i = 0; i < 4; ++i) {
        float v = bestv[i]; int c = bestc[i];
        #pragma unroll
        for (int off = 8; off; off >>= 1) {
            float ov = __shfl_xor(v, off, 16);
            int oc = __shfl_xor(c, off, 16);
            if (ov < v || (ov == v && oc < c)) { v = ov; c = oc; }
        }
        if (tx == 0) {
            int row = r0 + ty + 16 * i;
            idx_out[row] = c; idx_f[row] = (float)c;
            atomicAdd(&counts[c], 1u);
        }
    }
}

// ---------------- K3: gather + straight-through + loss partials ----------------
__global__ __launch_bounds__(256) void gather_kernel(
    const float* __restrict__ x, const float* __restrict__ emb,
    const int* __restrict__ idx, float* __restrict__ out,
    float* __restrict__ lpart, float* __restrict__ npart)
{
    int tid = threadIdx.x, lane = tid & 63, wid = tid >> 6;
    __shared__ float ls[4], ns[4];
    double lacc = 0.0, nacc = 0.0;
    for (int it = 0; it < 4; ++it) {
        int row = (blockIdx.x * 4 + wid) + it * (C_BLOCKS * 4);
        int c = idx[row];
        float4 xv = *(const float4*)(x + (size_t)row * D + lane * 4);
        float4 qv = *(const float4*)(emb + (size_t)c * D + lane * 4);
        float4 o;
        o.x = xv.x + (qv.x - xv.x); o.y = xv.y + (qv.y - xv.y);
        o.z = xv.z + (qv.z - xv.z); o.w = xv.w + (qv.w - xv.w);
        *(float4*)(out + (size_t)row * D + lane * 4) = o;
        float dx = xv.x - qv.x, dy = xv.y - qv.y, dz = xv.z - qv.z, dw = xv.w - qv.w;
        float ss = dx * dx + dy * dy + dz * dz + dw * dw;
        float sa = fabsf(xv.x) + fabsf(xv.y) + fabsf(xv.z) + fabsf(xv.w);
        #pragma unroll
        for (int off = 32; off; off >>= 1) {
            ss += __shfl_xor(ss, off);
            sa += __shfl_xor(sa, off);
        }
        if (sa > 0.0f) { lacc += (double)ss * (1.0 / 256.0); nacc += 1.0; }
    }
    if (lane == 0) { ls[wid] = (float)lacc; ns[wid] = (float)nacc; }
    __syncthreads();
    if (tid == 0) {
        lpart[blockIdx.x] = ls[0] + ls[1] + ls[2] + ls[3];
        npart[blockIdx.x] = ns[0] + ns[1] + ns[2] + ns[3];
    }
}

// ---------------- K4: perplexity + loss finalize ----------------
__global__ __launch_bounds__(256) void finalize_kernel(
    const unsigned* __restrict__ counts, const float* __restrict__ lpart,
    const float* __restrict__ npart, float* __restrict__ out)
{
    __shared__ double sd[256];
    __shared__ double sl[256];
    __shared__ double sn[256];
    int tid = threadIdx.x;
    double t = 0.0;
    for (int i = tid; i < M; i += 256) {
        double p = (double)counts[i] * (1.0 / 32768.0);
        t += p * log(p + 1e-10);
    }
    sd[tid] = t;
    double ln = 0.0, nn = 0.0;
    for (int i = tid; i < C_BLOCKS; i += 256) { ln += lpart[i]; nn += npart[i]; }
    sl[tid] = ln; sn[tid] = nn;
    __syncthreads();
    for (int s = 128; s; s >>= 1) {
        if (tid < s) { sd[tid] += sd[tid + s]; sl[tid] += sl[tid + s]; sn[tid] += sn[tid + s]; }
        __syncthreads();
    }
    if (tid == 0) {
        out[PERP_OFF] = (float)exp(-sd[0]);
        out[LOSS_OFF] = (float)(0.25 * sl[0] / sn[0]);
    }
}

extern "C" void kernel_launch(void* const* d_in, const int* in_sizes, int n_in,
                              void* d_out, int out_size, void* d_ws, size_t ws_size,
                              hipStream_t stream) {
    const float* x = (const float*)d_in[0];
    const float* emb = (const float*)d_in[1];
    float* out = (float*)d_out;
    char* ws = (char*)d_ws;

    float* enorm = (float*)(ws + WS_ENORM);
    unsigned* counts = (unsigned*)(ws + WS_COUNTS);
    int* idx = (int*)(ws + WS_IDX);
    float* lpart = (float*)(ws + WS_LPART);
    float* npart = (float*)(ws + WS_NPART);

    if (ws_size >= (size_t)WS_NEEDED) {
        f16* xh = (f16*)(ws + WS_XH);
        f16* xl = (f16*)(ws + WS_XL);
        f16* eh = (f16*)(ws + WS_EH);
        f16* el = (f16*)(ws + WS_EL);
        float2* cand = (float2*)(ws + WS_CAND);

        init_kernel<<<M / 4, 256, 0, stream>>>(emb, enorm, counts);
        convert_kernel<<<(N * D / 4) / 256, 256, 0, stream>>>(x, xh, xl, N * D / 4);
        convert_kernel<<<(M * D / 4) / 256, 256, 0, stream>>>(emb, eh, el, M * D / 4);
        argmin_mfma<<<1024, 256, 0, stream>>>(xh, xl, eh, el, enorm, cand);
        merge_kernel<<<N / 256, 256, 0, stream>>>(cand, counts, idx, out + IDX_OFF);
    } else {
        // fallback: small-ws layout (round-2 proven)
        enorm = (float*)(ws + 0);
        counts = (unsigned*)(ws + 16384);
        idx = (int*)(ws + 32768);
        lpart = (float*)(ws + 163840);
        npart = (float*)(ws + 172032);
        init_kernel<<<M / 4, 256, 0, stream>>>(emb, enorm, counts);
        argmin_fp32<<<N / BR, 256, 0, stream>>>(x, emb, enorm, counts, idx, out + IDX_OFF);
    }
    gather_kernel<<<C_BLOCKS, 256, 0, stream>>>(x, emb, idx, out, lpart, npart);
    finalize_kernel<<<1, 256, 0, stream>>>(counts, lpart, npart, out);
}

// Round 11
// 322.633 us; speedup vs baseline: 3.8543x; 1.0557x over previous
//
#include <hip/hip_runtime.h>
#include <math.h>
#include <stdint.h>

#define D 256
#define N 32768
#define M 4096

// output layout (floats): quantized | loss | indices | perplexity
#define LOSS_OFF 8388608
#define IDX_OFF  8388609
#define PERP_OFF 8421377

typedef _Float16 f16;
typedef _Float16 f16x8 __attribute__((ext_vector_type(8)));
typedef _Float16 f16x4 __attribute__((ext_vector_type(4)));
typedef float f32x4 __attribute__((ext_vector_type(4)));

// ---------- workspace layout (bytes), fp16-MFMA path ----------
#define WS_XH     0u
#define WS_XL     16777216u
#define WS_EH     33554432u
#define WS_EL     35651584u
#define WS_ENORM  37748736u
#define WS_COUNTS 37765120u
#define WS_IDX    37781504u
#define WS_CAND   37912576u   // float2[4][32768]
#define WS_LPART  38961152u
#define WS_NPART  38969344u
#define WS_NEEDED 38977536u
#define C_BLOCKS  2048

__device__ __forceinline__ void gload16(const void* g, void* l) {
    __builtin_amdgcn_global_load_lds(
        (const __attribute__((address_space(1))) uint32_t*)g,
        (__attribute__((address_space(3))) uint32_t*)l, 16, 0, 0);
}

#define MFMA16(a, b, c) __builtin_amdgcn_mfma_f32_16x16x32_f16((a), (b), (c), 0, 0, 0)

// ---------------- K1: embedding norms + zero counts ----------------
__global__ __launch_bounds__(256) void init_kernel(const float* __restrict__ emb,
                                                   float* __restrict__ enorm,
                                                   unsigned* __restrict__ counts) {
    int tid = threadIdx.x;
    int lane = tid & 63;
    int wid = tid >> 6;
    int m = blockIdx.x * 4 + wid;
    const float4* e4 = (const float4*)(emb + (size_t)m * D);
    float4 v = e4[lane];
    float s = v.x * v.x + v.y * v.y + v.z * v.z + v.w * v.w;
    #pragma unroll
    for (int off = 32; off; off >>= 1) s += __shfl_xor(s, off);
    if (lane == 0) enorm[m] = s;
    int gid = blockIdx.x * 256 + tid;
    if (gid < M) counts[gid] = 0u;
}

// ---------------- convert: f32 -> (hi fp16, lo fp16) ----------------
__global__ __launch_bounds__(256) void convert_kernel(const float* __restrict__ s,
                                                      f16* __restrict__ dh,
                                                      f16* __restrict__ dl, int n4) {
    int i = blockIdx.x * 256 + threadIdx.x;
    if (i >= n4) return;
    float4 v = ((const float4*)s)[i];
    f16 h0 = (f16)v.x, h1 = (f16)v.y, h2 = (f16)v.z, h3 = (f16)v.w;
    f16 l0 = (f16)(v.x - (float)h0), l1 = (f16)(v.y - (float)h1);
    f16 l2 = (f16)(v.z - (float)h2), l3 = (f16)(v.w - (float)h3);
    f16x4 hv; hv[0] = h0; hv[1] = h1; hv[2] = h2; hv[3] = h3;
    f16x4 lv; lv[0] = l0; lv[1] = l1; lv[2] = l2; lv[3] = l3;
    *(f16x4*)(dh + (size_t)i * 4) = hv;
    *(f16x4*)(dl + (size_t)i * 4) = lv;
}

// ---------------- K2 (MFMA, x-persistent): distance argmin ----------------
// x.e ~= xh.eh + xh.el + xl.eh.  Per block (128 rows x 1024 cols):
//   Xh resident in LDS (64 KB, slot-XOR swizzled), xl resident in regs,
//   E double-buffered [2][128][eh32|el32] prefetched 1 phase ahead.
// 64 phases = 8 ct x 8 kc; per phase/wave: 2 gload16 + 12 ds_read_b128 + 24 MFMA.
// 8 waves (512 thr): wr=wid>>1 (32-row strip), wc=wid&1 (64-col strip).
// Decode groups all 4 cs-blocks of an rb onto one XCD (L2 locality).
__global__ __launch_bounds__(512) void argmin_xp(
    const f16* __restrict__ xh, const f16* __restrict__ xl,
    const f16* __restrict__ eh, const f16* __restrict__ el,
    const float* __restrict__ enorm, float2* __restrict__ cand)
{
    extern __shared__ char smem[];
    f16* Xh = (f16*)smem;                          // [128][256] swizzled
    f16* EBa = (f16*)(smem + 65536);               // [2][128][64] swizzled
    float2 (*msm)[32] = (float2(*)[32])(smem + 65536);  // alias, epilogue only

    int tid = threadIdx.x;
    int lane = tid & 63;
    int wid = tid >> 6;          // 0..7
    int wr = wid >> 1;           // 0..3
    int wc = wid & 1;            // 0..1
    int b = blockIdx.x;
    int rb = (b & 7) * 32 + (b >> 5);   // XCD-grouped: 4 cs of one rb -> same XCD
    int cs = (b >> 3) & 3;
    int row0 = rb * 128;
    int rxor = lane & 7;

    // ---- prologue ----
    // Xh: 64 chunks of 1024B (2 rows x 512B), 8 per wave; LDS dest linear,
    // source slot pre-swizzled (rule #21).
    {
        int srow = lane >> 5, lslot = lane & 31;
        #pragma unroll
        for (int q = 0; q < 8; ++q) {
            int ch = wid * 8 + q;
            int row = ch * 2 + srow;
            int ss = lslot ^ (row & 7);
            gload16(xh + (size_t)(row0 + row) * D + ss * 8, smem + ch * 1024);
        }
    }
    // E phase-0 -> buf0: 16 chunks of 1024B (8 rows x 128B), 2 per wave
    {
        int srow = lane >> 3, lslot = lane & 7;
        int c0 = cs * 1024;
        #pragma unroll
        for (int q = 0; q < 2; ++q) {
            int ch = wid * 2 + q;
            int row = ch * 8 + srow;
            int ss = lslot ^ (row & 7);
            const f16* src = (ss < 4) ? eh : el;
            gload16(src + (size_t)(c0 + row) * D + (ss & 3) * 8,
                    smem + 65536 + ch * 1024);
        }
    }
    // xl -> regs (static-indexed, rule #20)
    f16x8 xlr[2][8];
    #pragma unroll
    for (int i = 0; i < 2; ++i) {
        int row = row0 + wr * 32 + i * 16 + (lane & 15);
        #pragma unroll
        for (int kc = 0; kc < 8; ++kc)
            xlr[i][kc] = *(const f16x8*)(xl + (size_t)row * D + kc * 32 + (lane >> 4) * 8);
    }
    __syncthreads();

    float bestv[2][4];
    int bestc[2][4];
    #pragma unroll
    for (int i = 0; i < 2; ++i)
        #pragma unroll
        for (int r = 0; r < 4; ++r) { bestv[i][r] = 3.4e38f; bestc[i][r] = 0; }

    for (int ct = 0; ct < 8; ++ct) {
        int c0 = (cs * 8 + ct) * 128;
        f32x4 acc[2][4];
        #pragma unroll
        for (int i = 0; i < 2; ++i)
            #pragma unroll
            for (int j = 0; j < 4; ++j) acc[i][j] = (f32x4)0.0f;

        #pragma unroll
        for (int kc = 0; kc < 8; ++kc) {
            // prefetch E for phase t+1 into buf (t+1)&1 (issue BEFORE compute)
            if (ct * 8 + kc < 63) {
                int t1 = ct * 8 + kc + 1;
                int ct1 = t1 >> 3, kc1 = t1 & 7, d1 = t1 & 1;
                int c01 = (cs * 8 + ct1) * 128;
                int srow = lane >> 3, lslot = lane & 7;
                #pragma unroll
                for (int q = 0; q < 2; ++q) {
                    int ch = wid * 2 + q;
                    int row = ch * 8 + srow;
                    int ss = lslot ^ (row & 7);
                    const f16* src = (ss < 4) ? eh : el;
                    gload16(src + (size_t)(c01 + row) * D + kc1 * 32 + (ss & 3) * 8,
                            smem + 65536 + d1 * 16384 + ch * 1024);
                }
            }
            // compute phase t on buf kc&1
            {
                const f16* EB = EBa + (kc & 1) * 8192;
                f16x8 ah[2], bh[4], bl[4];
                #pragma unroll
                for (int i = 0; i < 2; ++i) {
                    int row = wr * 32 + i * 16 + (lane & 15);
                    int sl = (kc * 4 + (lane >> 4)) ^ rxor;
                    ah[i] = *(const f16x8*)(Xh + row * 256 + sl * 8);
                }
                #pragma unroll
                for (int j = 0; j < 4; ++j) {
                    int row = wc * 64 + j * 16 + (lane & 15);
                    const f16* ebr = EB + row * 64;
                    bh[j] = *(const f16x8*)(ebr + (((lane >> 4)) ^ rxor) * 8);
                    bl[j] = *(const f16x8*)(ebr + ((4 + (lane >> 4)) ^ rxor) * 8);
                }
                #pragma unroll
                for (int i = 0; i < 2; ++i)
                    #pragma unroll
                    for (int j = 0; j < 4; ++j)
                        acc[i][j] = MFMA16(ah[i], bh[j], acc[i][j]);
                #pragma unroll
                for (int i = 0; i < 2; ++i)
                    #pragma unroll
                    for (int j = 0; j < 4; ++j)
                        acc[i][j] = MFMA16(ah[i], bl[j], acc[i][j]);
                #pragma unroll
                for (int i = 0; i < 2; ++i)
                    #pragma unroll
                    for (int j = 0; j < 4; ++j)
                        acc[i][j] = MFMA16(xlr[i][kc], bh[j], acc[i][j]);
            }
            __syncthreads();   // drains prefetch (had full compute window) + releases buf
        }
        // score = ||e||^2 - 2 x.e ; cols ascend with (ct, j) -> strict < keeps first
        float enj[4];
        #pragma unroll
        for (int j = 0; j < 4; ++j) enj[j] = enorm[c0 + wc * 64 + j * 16 + (lane & 15)];
        #pragma unroll
        for (int i = 0; i < 2; ++i)
            #pragma unroll
            for (int j = 0; j < 4; ++j) {
                int c = c0 + wc * 64 + j * 16 + (lane & 15);
                #pragma unroll
                for (int r = 0; r < 4; ++r) {
                    float s = enj[j] - 2.0f * acc[i][j][r];
                    if (s < bestv[i][r]) { bestv[i][r] = s; bestc[i][r] = c; }
                }
            }
    }

    // reduce across the 16 lanes (lane&15) holding the same rows
    float rv[2][4]; int rc[2][4];
    #pragma unroll
    for (int i = 0; i < 2; ++i)
        #pragma unroll
        for (int r = 0; r < 4; ++r) {
            float v = bestv[i][r]; int c = bestc[i][r];
            #pragma unroll
            for (int off = 8; off; off >>= 1) {
                float ov = __shfl_xor(v, off);
                int oc = __shfl_xor(c, off);
                if (ov < v || (ov == v && oc < c)) { v = ov; c = oc; }
            }
            rv[i][r] = v; rc[i][r] = c;
            if ((lane & 15) == 0 && wc == 1) {
                int rloc = i * 16 + (lane >> 4) * 4 + r;
                float2 p; p.x = v; p.y = __int_as_float(c);
                msm[wr][rloc] = p;   // EB dead after final phase barrier
            }
        }
    __syncthreads();
    if (wc == 0 && (lane & 15) == 0) {
        #pragma unroll
        for (int i = 0; i < 2; ++i)
            #pragma unroll
            for (int r = 0; r < 4; ++r) {
                int rloc = i * 16 + (lane >> 4) * 4 + r;
                float v = rv[i][r]; int c = rc[i][r];
                float2 o = msm[wr][rloc];
                float ov = o.x; int oc = __float_as_int(o.y);
                if (ov < v || (ov == v && oc < c)) { v = ov; c = oc; }
                float2 p; p.x = v; p.y = __int_as_float(c);
                cand[(size_t)cs * N + row0 + wr * 32 + rloc] = p;
            }
    }
}

// ---------------- merge 4 col-split candidates ----------------
__global__ __launch_bounds__(256) void merge_kernel(const float2* __restrict__ cand,
                                                    unsigned* __restrict__ counts,
                                                    int* __restrict__ idx_out,
                                                    float* __restrict__ idx_f) {
    int row = blockIdx.x * 256 + threadIdx.x;
    float bv = 3.4e38f; int bc = 0;
    #pragma unroll
    for (int cs = 0; cs < 4; ++cs) {
        float2 p = cand[(size_t)cs * N + row];
        int c = __float_as_int(p.y);
        if (p.x < bv || (p.x == bv && c < bc)) { bv = p.x; bc = c; }
    }
    idx_out[row] = bc;
    idx_f[row] = (float)bc;
    atomicAdd(&counts[bc], 1u);
}

// ---------------- fp32 fallback argmin (round-2 proven) ----------------
#define BR 64
#define BC 128
#define BK 64
__global__ __launch_bounds__(256) void argmin_fp32(
    const float* __restrict__ x, const float* __restrict__ emb,
    const float* __restrict__ enorm, unsigned* __restrict__ counts,
    int* __restrict__ idx_out, float* __restrict__ idx_f)
{
    __shared__ float xs[BR][65];
    __shared__ float es[BC][65];
    __shared__ float en_s[BC];
    int tid = threadIdx.x;
    int ty = tid >> 4, tx = tid & 15;
    int r0 = blockIdx.x * BR;
    float bestv[4]; int bestc[4];
    #pragma unroll
    for (int i = 0; i < 4; ++i) { bestv[i] = 3.4e38f; bestc[i] = 0; }
    for (int ct = 0; ct < M / BC; ++ct) {
        int c0 = ct * BC;
        float acc[4][8];
        #pragma unroll
        for (int i = 0; i < 4; ++i)
            #pragma unroll
            for (int j = 0; j < 8; ++j) acc[i][j] = 0.0f;
        for (int kt = 0; kt < D / BK; ++kt) {
            __syncthreads();
            #pragma unroll
            for (int p = 0; p < 4; ++p) {
                int l = p * 256 + tid, r = l >> 4, k4 = l & 15;
                float4 v = *(const float4*)(x + (size_t)(r0 + r) * D + kt * BK + k4 * 4);
                xs[r][k4 * 4] = v.x; xs[r][k4 * 4 + 1] = v.y;
                xs[r][k4 * 4 + 2] = v.z; xs[r][k4 * 4 + 3] = v.w;
            }
            #pragma unroll
            for (int p = 0; p < 8; ++p) {
                int l = p * 256 + tid, r = l >> 4, k4 = l & 15;
                float4 v = *(const float4*)(emb + (size_t)(c0 + r) * D + kt * BK + k4 * 4);
                es[r][k4 * 4] = v.x; es[r][k4 * 4 + 1] = v.y;
                es[r][k4 * 4 + 2] = v.z; es[r][k4 * 4 + 3] = v.w;
            }
            if (kt == 0 && tid < BC) en_s[tid] = enorm[c0 + tid];
            __syncthreads();
            #pragma unroll 8
            for (int k = 0; k < BK; ++k) {
                float xv[4], ev[8];
                #pragma unroll
                for (int i = 0; i < 4; ++i) xv[i] = xs[ty + 16 * i][k];
                #pragma unroll
                for (int j = 0; j < 8; ++j) ev[j] = es[tx + 16 * j][k];
                #pragma unroll
                for (int i = 0; i < 4; ++i)
                    #pragma unroll
                    for (int j = 0; j < 8; ++j)
                        acc[i][j] = fmaf(xv[i], ev[j], acc[i][j]);
            }
        }
        #pragma unroll
        for (int i = 0; i < 4; ++i)
            #pragma unroll
            for (int j = 0; j < 8; ++j) {
                int c = c0 + tx + 16 * j;
                float s = en_s[tx + 16 * j] - 2.0f * acc[i][j];
                if (s < bestv[i]) { bestv[i] = s; bestc[i] = c; }
            }
    }
    #pragma unroll
    for (int i = 0; i < 4; ++i) {
        float v = bestv[i]; int c = bestc[i];
        #pragma unroll
        for (int off = 8; off; off >>= 1) {
            float ov = __shfl_xor(v, off, 16);
            int oc = __shfl_xor(c, off, 16);
            if (ov < v || (ov == v && oc < c)) { v = ov; c = oc; }
        }
        if (tx == 0) {
            int row = r0 + ty + 16 * i;
            idx_out[row] = c; idx_f[row] = (float)c;
            atomicAdd(&counts[c], 1u);
        }
    }
}

// ---------------- K3: gather + straight-through + loss partials ----------------
__global__ __launch_bounds__(256) void gather_kernel(
    const float* __restrict__ x, const float* __restrict__ emb,
    const int* __restrict__ idx, float* __restrict__ out,
    float* __restrict__ lpart, float* __restrict__ npart)
{
    int tid = threadIdx.x, lane = tid & 63, wid = tid >> 6;
    __shared__ float ls[4], ns[4];
    double lacc = 0.0, nacc = 0.0;
    for (int it = 0; it < 4; ++it) {
        int row = (blockIdx.x * 4 + wid) + it * (C_BLOCKS * 4);
        int c = idx[row];
        float4 xv = *(const float4*)(x + (size_t)row * D + lane * 4);
        float4 qv = *(const float4*)(emb + (size_t)c * D + lane * 4);
        float4 o;
        o.x = xv.x + (qv.x - xv.x); o.y = xv.y + (qv.y - xv.y);
        o.z = xv.z + (qv.z - xv.z); o.w = xv.w + (qv.w - xv.w);
        *(float4*)(out + (size_t)row * D + lane * 4) = o;
        float dx = xv.x - qv.x, dy = xv.y - qv.y, dz = xv.z - qv.z, dw = xv.w - qv.w;
        float ss = dx * dx + dy * dy + dz * dz + dw * dw;
        float sa = fabsf(xv.x) + fabsf(xv.y) + fabsf(xv.z) + fabsf(xv.w);
        #pragma unroll
        for (int off = 32; off; off >>= 1) {
            ss += __shfl_xor(ss, off);
            sa += __shfl_xor(sa, off);
        }
        if (sa > 0.0f) { lacc += (double)ss * (1.0 / 256.0); nacc += 1.0; }
    }
    if (lane == 0) { ls[wid] = (float)lacc; ns[wid] = (float)nacc; }
    __syncthreads();
    if (tid == 0) {
        lpart[blockIdx.x] = ls[0] + ls[1] + ls[2] + ls[3];
        npart[blockIdx.x] = ns[0] + ns[1] + ns[2] + ns[3];
    }
}

// ---------------- K4: perplexity + loss finalize ----------------
__global__ __launch_bounds__(256) void finalize_kernel(
    const unsigned* __restrict__ counts, const float* __restrict__ lpart,
    const float* __restrict__ npart, float* __restrict__ out)
{
    __shared__ double sd[256];
    __shared__ double sl[256];
    __shared__ double sn[256];
    int tid = threadIdx.x;
    double t = 0.0;
    for (int i = tid; i < M; i += 256) {
        double p = (double)counts[i] * (1.0 / 32768.0);
        t += p * log(p + 1e-10);
    }
    sd[tid] = t;
    double ln = 0.0, nn = 0.0;
    for (int i = tid; i < C_BLOCKS; i += 256) { ln += lpart[i]; nn += npart[i]; }
    sl[tid] = ln; sn[tid] = nn;
    __syncthreads();
    for (int s = 128; s; s >>= 1) {
        if (tid < s) { sd[tid] += sd[tid + s]; sl[tid] += sl[tid + s]; sn[tid] += sn[tid + s]; }
        __syncthreads();
    }
    if (tid == 0) {
        out[PERP_OFF] = (float)exp(-sd[0]);
        out[LOSS_OFF] = (float)(0.25 * sl[0] / sn[0]);
    }
}

extern "C" void kernel_launch(void* const* d_in, const int* in_sizes, int n_in,
                              void* d_out, int out_size, void* d_ws, size_t ws_size,
                              hipStream_t stream) {
    const float* x = (const float*)d_in[0];
    const float* emb = (const float*)d_in[1];
    float* out = (float*)d_out;
    char* ws = (char*)d_ws;

    float* enorm = (float*)(ws + WS_ENORM);
    unsigned* counts = (unsigned*)(ws + WS_COUNTS);
    int* idx = (int*)(ws + WS_IDX);
    float* lpart = (float*)(ws + WS_LPART);
    float* npart = (float*)(ws + WS_NPART);

    if (ws_size >= (size_t)WS_NEEDED) {
        f16* xh = (f16*)(ws + WS_XH);
        f16* xl = (f16*)(ws + WS_XL);
        f16* eh = (f16*)(ws + WS_EH);
        f16* el = (f16*)(ws + WS_EL);
        float2* cand = (float2*)(ws + WS_CAND);

        init_kernel<<<M / 4, 256, 0, stream>>>(emb, enorm, counts);
        convert_kernel<<<(N * D / 4) / 256, 256, 0, stream>>>(x, xh, xl, N * D / 4);
        convert_kernel<<<(M * D / 4) / 256, 256, 0, stream>>>(emb, eh, el, M * D / 4);
        argmin_xp<<<1024, 512, 98304, stream>>>(xh, xl, eh, el, enorm, cand);
        merge_kernel<<<N / 256, 256, 0, stream>>>(cand, counts, idx, out + IDX_OFF);
    } else {
        // fallback: small-ws layout (round-2 proven)
        enorm = (float*)(ws + 0);
        counts = (unsigned*)(ws + 16384);
        idx = (int*)(ws + 32768);
        lpart = (float*)(ws + 163840);
        npart = (float*)(ws + 172032);
        init_kernel<<<M / 4, 256, 0, stream>>>(emb, enorm, counts);
        argmin_fp32<<<N / BR, 256, 0, stream>>>(x, emb, enorm, counts, idx, out + IDX_OFF);
    }
    gather_kernel<<<C_BLOCKS, 256, 0, stream>>>(x, emb, idx, out, lpart, npart);
    finalize_kernel<<<1, 256, 0, stream>>>(counts, lpart, npart, out);
}